// Round 14
// baseline (234.224 us; speedup 1.0000x reference)
//
#include <hip/hip_runtime.h>
#include <hip/hip_bf16.h>

// Mlp_moe: patch MLP + 6-class 2-route MoE on cls tokens.
// Round 14: round-13 locked; re-add fc1 XCD-chunked swizzle (dur-neutral standalone,
// expected small + under backfill L2 pressure; R12 fetch-regression read was confounded).

typedef __bf16 bf16x8 __attribute__((ext_vector_type(8)));
typedef float f32x4 __attribute__((ext_vector_type(4)));
typedef unsigned short u16;

#define DEVINL __device__ __forceinline__

DEVINL u16 f2bf(float f) {  // native cast: RNE, compiler may pack as v_cvt_pk_bf16_f32
  __bf16 h = (__bf16)f;
  return __builtin_bit_cast(u16, h);
}

// Winitzki erf: abs err ~2e-4 (vs bf16 rounding 0.008), branch-free.
DEVINL float gelu_fast(float v) {
  const float x2 = 0.5f * v * v;
  const float t = x2 * (1.27323954f + 0.147f * x2) / (1.0f + 0.147f * x2);
  const float r = sqrtf(fmaxf(1.0f - __expf(-t), 0.0f));
  const float e = copysignf(r, v);
  return 0.5f * v * (1.0f + e);
}

DEVINL void async_load16(const void* g, void* l) {
  __builtin_amdgcn_global_load_lds(
      (const __attribute__((address_space(1))) unsigned int*)g,
      (__attribute__((address_space(3))) unsigned int*)l, 16, 0, 0);
}

#define MFMA16 __builtin_amdgcn_mfma_f32_16x16x32_bf16

// ---------------- dispatch 1: x split + w1/wai cvt + gate ----------------
__global__ void cvt_gate(const float* __restrict__ x, u16* __restrict__ xc, u16* __restrict__ xp,
                         const float* __restrict__ fc1w, u16* __restrict__ w1,
                         const float* __restrict__ aiw, u16* __restrict__ wai,
                         const float* __restrict__ gate_pair,
                         const float* __restrict__ balance_bias,
                         int* __restrict__ rstar, float* __restrict__ wstar) {
  int b = blockIdx.x;
  if (b < 9744) {
    const int e = (b * 256 + threadIdx.x) * 4;
    const int t = e / 768, dd = e % 768;
    const int bb = t / 203, i = t % 203;
    const float4 v = *(const float4*)(x + e);
    ushort4 u;
    u.x = f2bf(v.x); u.y = f2bf(v.y); u.z = f2bf(v.z); u.w = f2bf(v.w);
    if (i < 6) *(ushort4*)(xc + (size_t)(bb * 6 + i) * 768 + dd) = u;
    else       *(ushort4*)(xp + (size_t)(bb * 197 + (i - 6)) * 768 + dd) = u;
    return;
  }
  b -= 9744;
  if (b < 13824) {
    const float* s; u16* d;
    if (b < 2304) { s = fc1w; d = w1; }
    else { s = aiw; d = wai; b -= 2304; }
    const int i = (b * 256 + threadIdx.x) * 4;
    const float4 v = *(const float4*)(s + i);
    ushort4 u;
    u.x = f2bf(v.x); u.y = f2bf(v.y); u.z = f2bf(v.z); u.w = f2bf(v.w);
    *(ushort4*)(d + i) = u;
    return;
  }
  b -= 13824;  // gate: 96 blocks x 4 waves
  const int lane = threadIdx.x & 63, wid = threadIdx.x >> 6;
  const int idx = b * 4 + wid;
  const int bb = idx / 6, n = idx % 6;
  const float* xv = x + (size_t)(bb * 203 + n) * 768;
  const float* w0 = gate_pair + (size_t)(n * 2 + 0) * 768;
  const float* w1g = gate_pair + (size_t)(n * 2 + 1) * 768;
  double xx = 0, a00 = 0, a11 = 0, p0 = 0, p1 = 0;
  for (int d = lane; d < 768; d += 64) {
    double xd = xv[d], g0 = w0[d], g1 = w1g[d];
    xx += xd * xd; a00 += g0 * g0; a11 += g1 * g1; p0 += xd * g0; p1 += xd * g1;
  }
#pragma unroll
  for (int off = 32; off; off >>= 1) {
    xx  += __shfl_xor(xx, off);
    a00 += __shfl_xor(a00, off);
    a11 += __shfl_xor(a11, off);
    p0  += __shfl_xor(p0, off);
    p1  += __shfl_xor(p1, off);
  }
  if (lane == 0) {
    double nx = fmax(sqrt(xx), 1e-12), n0 = fmax(sqrt(a00), 1e-12), n1 = fmax(sqrt(a11), 1e-12);
    double l0 = p0 / (nx * n0) + (double)balance_bias[n * 2 + 0];
    double l1 = p1 / (nx * n1) + (double)balance_bias[n * 2 + 1];
    const int r = (l1 > l0) ? 1 : 0;
    double m = fmax(l0, l1);
    double e0 = exp(l0 - m), e1 = exp(l1 - m);
    rstar[idx] = r;
    wstar[idx] = (float)(((r == 1) ? e1 : e0) / (e0 + e1));
  }
}

// ---------------- round-1 gemm body (best measured) ----------------
template <int EPI>
DEVINL void gemm_body(const u16* __restrict__ A, const u16* __restrict__ B,
                      const float* __restrict__ bias, void* __restrict__ Cout,
                      int M, int K, int ldc, int bx, int by, u16* As, u16* Bs) {
  const int tid = threadIdx.x;
  const int lane = tid & 63, wid = tid >> 6;
  const int wr = wid >> 1, wc = wid & 1;
  const int tm = by * 128, tn = bx * 128;
  const int rA = lane >> 3, sA = lane & 7;
  const int ksteps = K >> 6;

  f32x4 acc[4][4] = {};

  for (int ks = 0; ks < ksteps; ++ks) {
    const int k0 = ks << 6;
#pragma unroll
    for (int c = 0; c < 4; ++c) {
      const int chunk = wid * 4 + c;
      const int row   = chunk * 8 + rA;
      int grow = tm + row;
      grow = grow < M ? grow : (M - 1);  // clamp tail rows (never stored)
      const int slot = sA ^ (row & 7);
      async_load16(A + (size_t)grow * K + k0 + slot * 8, (char*)As + chunk * 1024);
    }
#pragma unroll
    for (int c = 0; c < 4; ++c) {
      const int chunk = wid * 4 + c;
      const int row   = chunk * 8 + rA;
      const int slot  = sA ^ (row & 7);
      async_load16(B + (size_t)(tn + row) * K + k0 + slot * 8, (char*)Bs + chunk * 1024);
    }
    __syncthreads();  // vmcnt(0) drain: staged data visible
#pragma unroll
    for (int kk = 0; kk < 2; ++kk) {
      bf16x8 af[4], bfv[4];
#pragma unroll
      for (int im = 0; im < 4; ++im) {
        const int R = wr * 64 + im * 16 + (lane & 15);
        const int s = (kk * 4 + (lane >> 4)) ^ (R & 7);
        af[im] = *(const bf16x8*)((const char*)As + R * 128 + s * 16);
      }
#pragma unroll
      for (int in_ = 0; in_ < 4; ++in_) {
        const int R = wc * 64 + in_ * 16 + (lane & 15);
        const int s = (kk * 4 + (lane >> 4)) ^ (R & 7);
        bfv[in_] = *(const bf16x8*)((const char*)Bs + R * 128 + s * 16);
      }
#pragma unroll
      for (int im = 0; im < 4; ++im)
#pragma unroll
        for (int in_ = 0; in_ < 4; ++in_)
          acc[im][in_] = MFMA16(af[im], bfv[in_], acc[im][in_], 0, 0, 0);
    }
    __syncthreads();  // protect single buffer
  }

  const int cn = lane & 15, cr4 = (lane >> 4) * 4;
  const int col0 = tn + wc * 64 + cn;
  const int r0 = tm + wr * 64;
  int b197 = 0, p197 = 0;
  if (EPI == 1) { b197 = r0 / 197; p197 = r0 % 197; }
#pragma unroll
  for (int im = 0; im < 4; ++im) {
#pragma unroll
    for (int in_ = 0; in_ < 4; ++in_) {
      const int col = col0 + in_ * 16;
      const float bv = bias[col];
#pragma unroll
      for (int j = 0; j < 4; ++j) {
        const int off = im * 16 + cr4 + j;
        const int row = r0 + off;
        if (row < M) {
          const float v = acc[im][in_][j] + bv;
          if (EPI == 0) {
            ((u16*)Cout)[(size_t)row * ldc + col] = f2bf(gelu_fast(v));
          } else {
            int pp = p197 + off, bb = b197;
            if (pp >= 197) { pp -= 197; ++bb; }
            ((float*)Cout)[((size_t)(bb * 203 + 6 + pp)) * 768 + col] = v;
          }
        }
      }
    }
  }
}

// ---------------- round-7 cand body (32x128 tile, dbuf 2-phase) ----------------
DEVINL void cand_body(const u16* __restrict__ hid, const u16* __restrict__ wao,
                      const float* __restrict__ bout, const int* __restrict__ rstar,
                      const float* __restrict__ wstar, float* __restrict__ out,
                      int bx, int g, int bz, char* smem) {
  const int n = g >> 1, r = g & 1;
  const int src_a = (r == 0) ? (n >> 1) : (3 + (n & 1));
  const int dst_a = (r == 1) ? (n >> 1) : (3 + (n & 1));
  const int tn = bx * 128;
  const int b0 = bz * 32;
  const int tid = threadIdx.x, lane = tid & 63, wid = tid >> 6;
  const u16* Bbase = wao + (size_t)dst_a * 768 * 3072;
  const u16* Abase = hid + (size_t)src_a * 3072 + (size_t)n * 15360;

  f32x4 acc[2][2] = {};

  auto stage = [&](int buf, int t) {
    const int k0 = t << 6;
    {
      const int row = tid >> 3;
      const int slA = (tid & 7) ^ (row & 7);
      async_load16(Abase + (size_t)(b0 + row) * 6 * 15360 + k0 + slA * 8,
                   smem + buf * 4096 + row * 128 + (tid & 7) * 16);
    }
#pragma unroll
    for (int j = 0; j < 4; ++j) {
      const int row = j * 32 + (tid >> 3);
      const int slB = (tid & 7) ^ (row & 7);
      async_load16(Bbase + (size_t)(tn + row) * 3072 + k0 + slB * 8,
                   smem + 8192 + buf * 16384 + row * 128 + (tid & 7) * 16);
    }
  };
  auto compute = [&](int buf) {
    const u16* as = (const u16*)(smem + buf * 4096);
    const u16* bs = (const u16*)(smem + 8192 + buf * 16384);
#pragma unroll
    for (int kk = 0; kk < 2; ++kk) {
      bf16x8 af[2], bfv[2];
#pragma unroll
      for (int im = 0; im < 2; ++im) {
        const int R = im * 16 + (lane & 15);
        const int s = (kk * 4 + (lane >> 4)) ^ (R & 7);
        af[im] = *(const bf16x8*)(as + R * 64 + s * 8);
      }
#pragma unroll
      for (int q = 0; q < 2; ++q) {
        const int R = wid * 32 + q * 16 + (lane & 15);
        const int s = (kk * 4 + (lane >> 4)) ^ (R & 7);
        bfv[q] = *(const bf16x8*)(bs + R * 64 + s * 8);
      }
#pragma unroll
      for (int im = 0; im < 2; ++im)
#pragma unroll
        for (int q = 0; q < 2; ++q)
          acc[im][q] = MFMA16(af[im], bfv[q], acc[im][q], 0, 0, 0);
    }
  };

  stage(0, 0);
  __syncthreads();
  for (int t = 0; t < 48; ++t) {
    if (t + 1 < 48) stage((t + 1) & 1, t + 1);
    compute(t & 1);
    __syncthreads();
  }

  const int cn = lane & 15, cr4 = (lane >> 4) * 4;
#pragma unroll
  for (int im = 0; im < 2; ++im)
#pragma unroll
    for (int q = 0; q < 2; ++q) {
      const int col = tn + wid * 32 + q * 16 + cn;
      const float bv = bout[dst_a * 768 + col];
#pragma unroll
      for (int j = 0; j < 4; ++j) {
        const int b = b0 + im * 16 + cr4 + j;
        const int idx = b * 6 + n;
        if (rstar[idx] == r)
          out[((size_t)(b * 203 + n)) * 768 + col] = (acc[im][q][j] + bv) * wstar[idx];
      }
    }
}

// ---------------- dispatch 2: fc1 (2376, XCD-swizzled) + hid (360) + w2/wao cvt backfill ----------------
__global__ __launch_bounds__(256, 2) void gemm_f1(
    const u16* __restrict__ xp, const u16* __restrict__ w1, const float* __restrict__ fc1b,
    u16* __restrict__ hb,
    const u16* __restrict__ xc, const u16* __restrict__ wai, const float* __restrict__ aib,
    u16* __restrict__ hidb,
    const float* __restrict__ fc2w, u16* __restrict__ w2,
    const float* __restrict__ aow, u16* __restrict__ wao) {
  __shared__ u16 As[128 * 64];
  __shared__ u16 Bs[128 * 64];
  int id = blockIdx.x;
  if (id < 2376) {
    id = (id & 7) * 297 + (id >> 3);  // 2376 = 8*297, bijective XCD chunking
    gemm_body<0>(xp, w1, fc1b, hb, 12608, 768, 3072, id % 24, id / 24, As, Bs);
  } else if (id < 2736) {
    id -= 2376;
    gemm_body<0>(xc, wai, aib, hidb, 384, 768, 15360, id % 120, id / 120, As, Bs);
  } else {
    // w2 (2304) + wao (11520) conversions: consumed only by gemm_f2; backfill final round.
    id -= 2736;
    const float* s; u16* d;
    if (id < 2304) { s = fc2w; d = w2; }
    else { s = aow; d = wao; id -= 2304; }
    const int i = (id * 256 + threadIdx.x) * 4;
    const float4 v = *(const float4*)(s + i);
    ushort4 u;
    u.x = f2bf(v.x); u.y = f2bf(v.y); u.z = f2bf(v.z); u.w = f2bf(v.w);
    *(ushort4*)(d + i) = u;
  }
}

// ---------------- dispatch 3: fc2 (594, XCD-swizzled) + cand (144) ----------------
__global__ __launch_bounds__(256, 2) void gemm_f2(
    const u16* __restrict__ hb, const u16* __restrict__ w2, const float* __restrict__ fc2b,
    float* __restrict__ out,
    const u16* __restrict__ hidb, const u16* __restrict__ wao, const float* __restrict__ aob,
    const int* __restrict__ rstar, const float* __restrict__ wstar) {
  __shared__ char smem[40960];
  int id = blockIdx.x;
  if (id < 594) {
    // m204 bijective chunking for nwg=594: q=74, r=2
    const int xcd = id & 7, k = id >> 3;
    id = (xcd < 2 ? xcd * 75 : 150 + (xcd - 2) * 74) + k;
    gemm_body<1>(hb, w2, fc2b, out, 12608, 3072, 768, id % 6, id / 6,
                 (u16*)smem, (u16*)(smem + 16384));
  } else {
    id -= 594;
    cand_body(hidb, wao, aob, rstar, wstar, out, id % 6, (id / 6) % 12, id / 72, smem);
  }
}

// ---------------- launch ----------------
extern "C" void kernel_launch(void* const* d_in, const int* in_sizes, int n_in,
                              void* d_out, int out_size, void* d_ws, size_t ws_size,
                              hipStream_t stream) {
  const float* x     = (const float*)d_in[0];
  const float* fc1w  = (const float*)d_in[1];
  const float* fc1b  = (const float*)d_in[2];
  const float* fc2w  = (const float*)d_in[3];
  const float* fc2b  = (const float*)d_in[4];
  const float* gpair = (const float*)d_in[5];
  const float* aiw   = (const float*)d_in[6];
  const float* aib   = (const float*)d_in[7];
  const float* aow   = (const float*)d_in[8];
  const float* aob   = (const float*)d_in[9];
  const float* bbias = (const float*)d_in[10];
  float* out = (float*)d_out;

  char* ws = (char*)d_ws;
  u16* xp   = (u16*)(ws + 0);          // 12608x768 bf16
  u16* xc   = (u16*)(ws + 19365888);   // 384x768
  u16* w1   = (u16*)(ws + 19955712);   // 3072x768
  u16* w2   = (u16*)(ws + 24674304);   // 768x3072
  u16* wai  = (u16*)(ws + 29392896);   // 5x3072x768
  u16* wao  = (u16*)(ws + 52985856);   // 5x768x3072
  u16* hb   = (u16*)(ws + 76578816);   // 12608x3072
  u16* hid  = (u16*)(ws + 154042368);  // 384x15360
  int*   rstar = (int*)(ws + 165838848);
  float* wstar = (float*)(ws + 165840384);
  if (ws_size < 165841920) return;

  // dispatch 1: x split + w1/wai cvt + gate (23664 blocks)
  cvt_gate<<<23664, 256, 0, stream>>>(x, xc, xp, fc1w, w1, aiw, wai,
                                      gpair, bbias, rstar, wstar);
  // dispatch 2: fc1 + hid_all + w2/wao cvt backfill (16560 blocks)
  gemm_f1<<<16560, 256, 0, stream>>>(xp, w1, fc1b, hb, xc, wai, aib, hid,
                                     fc2w, w2, aow, wao);
  // dispatch 3: fc2 + route candidates (738 blocks)
  gemm_f2<<<738, 256, 0, stream>>>(hb, w2, fc2b, out, hid, wao, aob, rstar, wstar);
}

// Round 15
// 231.909 us; speedup vs baseline: 1.0100x; 1.0100x over previous
//
#include <hip/hip_runtime.h>
#include <hip/hip_bf16.h>

// Mlp_moe: patch MLP + 6-class 2-route MoE on cls tokens.
// Round 15: revert to round-13 (best measured, 231.5us). fc1 XCD swizzle removed
// (round-14 A/B: +2.7us, +19MB fetch). fc2 swizzle kept. Structure locked:
//   D1: x split + w1/wai cvt + gate
//   D2: fc1 GEMM + hid GEMM + w2/wao cvt tail-backfill
//   D3: fc2 GEMM (XCD-swizzled) + cand GEMM

typedef __bf16 bf16x8 __attribute__((ext_vector_type(8)));
typedef float f32x4 __attribute__((ext_vector_type(4)));
typedef unsigned short u16;

#define DEVINL __device__ __forceinline__

DEVINL u16 f2bf(float f) {  // native cast: RNE, compiler may pack as v_cvt_pk_bf16_f32
  __bf16 h = (__bf16)f;
  return __builtin_bit_cast(u16, h);
}

// Winitzki erf: abs err ~2e-4 (vs bf16 rounding 0.008), branch-free.
DEVINL float gelu_fast(float v) {
  const float x2 = 0.5f * v * v;
  const float t = x2 * (1.27323954f + 0.147f * x2) / (1.0f + 0.147f * x2);
  const float r = sqrtf(fmaxf(1.0f - __expf(-t), 0.0f));
  const float e = copysignf(r, v);
  return 0.5f * v * (1.0f + e);
}

DEVINL void async_load16(const void* g, void* l) {
  __builtin_amdgcn_global_load_lds(
      (const __attribute__((address_space(1))) unsigned int*)g,
      (__attribute__((address_space(3))) unsigned int*)l, 16, 0, 0);
}

#define MFMA16 __builtin_amdgcn_mfma_f32_16x16x32_bf16

// ---------------- dispatch 1: x split + w1/wai cvt + gate ----------------
__global__ void cvt_gate(const float* __restrict__ x, u16* __restrict__ xc, u16* __restrict__ xp,
                         const float* __restrict__ fc1w, u16* __restrict__ w1,
                         const float* __restrict__ aiw, u16* __restrict__ wai,
                         const float* __restrict__ gate_pair,
                         const float* __restrict__ balance_bias,
                         int* __restrict__ rstar, float* __restrict__ wstar) {
  int b = blockIdx.x;
  if (b < 9744) {
    const int e = (b * 256 + threadIdx.x) * 4;
    const int t = e / 768, dd = e % 768;
    const int bb = t / 203, i = t % 203;
    const float4 v = *(const float4*)(x + e);
    ushort4 u;
    u.x = f2bf(v.x); u.y = f2bf(v.y); u.z = f2bf(v.z); u.w = f2bf(v.w);
    if (i < 6) *(ushort4*)(xc + (size_t)(bb * 6 + i) * 768 + dd) = u;
    else       *(ushort4*)(xp + (size_t)(bb * 197 + (i - 6)) * 768 + dd) = u;
    return;
  }
  b -= 9744;
  if (b < 13824) {
    const float* s; u16* d;
    if (b < 2304) { s = fc1w; d = w1; }
    else { s = aiw; d = wai; b -= 2304; }
    const int i = (b * 256 + threadIdx.x) * 4;
    const float4 v = *(const float4*)(s + i);
    ushort4 u;
    u.x = f2bf(v.x); u.y = f2bf(v.y); u.z = f2bf(v.z); u.w = f2bf(v.w);
    *(ushort4*)(d + i) = u;
    return;
  }
  b -= 13824;  // gate: 96 blocks x 4 waves
  const int lane = threadIdx.x & 63, wid = threadIdx.x >> 6;
  const int idx = b * 4 + wid;
  const int bb = idx / 6, n = idx % 6;
  const float* xv = x + (size_t)(bb * 203 + n) * 768;
  const float* w0 = gate_pair + (size_t)(n * 2 + 0) * 768;
  const float* w1g = gate_pair + (size_t)(n * 2 + 1) * 768;
  double xx = 0, a00 = 0, a11 = 0, p0 = 0, p1 = 0;
  for (int d = lane; d < 768; d += 64) {
    double xd = xv[d], g0 = w0[d], g1 = w1g[d];
    xx += xd * xd; a00 += g0 * g0; a11 += g1 * g1; p0 += xd * g0; p1 += xd * g1;
  }
#pragma unroll
  for (int off = 32; off; off >>= 1) {
    xx  += __shfl_xor(xx, off);
    a00 += __shfl_xor(a00, off);
    a11 += __shfl_xor(a11, off);
    p0  += __shfl_xor(p0, off);
    p1  += __shfl_xor(p1, off);
  }
  if (lane == 0) {
    double nx = fmax(sqrt(xx), 1e-12), n0 = fmax(sqrt(a00), 1e-12), n1 = fmax(sqrt(a11), 1e-12);
    double l0 = p0 / (nx * n0) + (double)balance_bias[n * 2 + 0];
    double l1 = p1 / (nx * n1) + (double)balance_bias[n * 2 + 1];
    const int r = (l1 > l0) ? 1 : 0;
    double m = fmax(l0, l1);
    double e0 = exp(l0 - m), e1 = exp(l1 - m);
    rstar[idx] = r;
    wstar[idx] = (float)(((r == 1) ? e1 : e0) / (e0 + e1));
  }
}

// ---------------- round-1 gemm body (best measured) ----------------
template <int EPI>
DEVINL void gemm_body(const u16* __restrict__ A, const u16* __restrict__ B,
                      const float* __restrict__ bias, void* __restrict__ Cout,
                      int M, int K, int ldc, int bx, int by, u16* As, u16* Bs) {
  const int tid = threadIdx.x;
  const int lane = tid & 63, wid = tid >> 6;
  const int wr = wid >> 1, wc = wid & 1;
  const int tm = by * 128, tn = bx * 128;
  const int rA = lane >> 3, sA = lane & 7;
  const int ksteps = K >> 6;

  f32x4 acc[4][4] = {};

  for (int ks = 0; ks < ksteps; ++ks) {
    const int k0 = ks << 6;
#pragma unroll
    for (int c = 0; c < 4; ++c) {
      const int chunk = wid * 4 + c;
      const int row   = chunk * 8 + rA;
      int grow = tm + row;
      grow = grow < M ? grow : (M - 1);  // clamp tail rows (never stored)
      const int slot = sA ^ (row & 7);
      async_load16(A + (size_t)grow * K + k0 + slot * 8, (char*)As + chunk * 1024);
    }
#pragma unroll
    for (int c = 0; c < 4; ++c) {
      const int chunk = wid * 4 + c;
      const int row   = chunk * 8 + rA;
      const int slot  = sA ^ (row & 7);
      async_load16(B + (size_t)(tn + row) * K + k0 + slot * 8, (char*)Bs + chunk * 1024);
    }
    __syncthreads();  // vmcnt(0) drain: staged data visible
#pragma unroll
    for (int kk = 0; kk < 2; ++kk) {
      bf16x8 af[4], bfv[4];
#pragma unroll
      for (int im = 0; im < 4; ++im) {
        const int R = wr * 64 + im * 16 + (lane & 15);
        const int s = (kk * 4 + (lane >> 4)) ^ (R & 7);
        af[im] = *(const bf16x8*)((const char*)As + R * 128 + s * 16);
      }
#pragma unroll
      for (int in_ = 0; in_ < 4; ++in_) {
        const int R = wc * 64 + in_ * 16 + (lane & 15);
        const int s = (kk * 4 + (lane >> 4)) ^ (R & 7);
        bfv[in_] = *(const bf16x8*)((const char*)Bs + R * 128 + s * 16);
      }
#pragma unroll
      for (int im = 0; im < 4; ++im)
#pragma unroll
        for (int in_ = 0; in_ < 4; ++in_)
          acc[im][in_] = MFMA16(af[im], bfv[in_], acc[im][in_], 0, 0, 0);
    }
    __syncthreads();  // protect single buffer
  }

  const int cn = lane & 15, cr4 = (lane >> 4) * 4;
  const int col0 = tn + wc * 64 + cn;
  const int r0 = tm + wr * 64;
  int b197 = 0, p197 = 0;
  if (EPI == 1) { b197 = r0 / 197; p197 = r0 % 197; }
#pragma unroll
  for (int im = 0; im < 4; ++im) {
#pragma unroll
    for (int in_ = 0; in_ < 4; ++in_) {
      const int col = col0 + in_ * 16;
      const float bv = bias[col];
#pragma unroll
      for (int j = 0; j < 4; ++j) {
        const int off = im * 16 + cr4 + j;
        const int row = r0 + off;
        if (row < M) {
          const float v = acc[im][in_][j] + bv;
          if (EPI == 0) {
            ((u16*)Cout)[(size_t)row * ldc + col] = f2bf(gelu_fast(v));
          } else {
            int pp = p197 + off, bb = b197;
            if (pp >= 197) { pp -= 197; ++bb; }
            ((float*)Cout)[((size_t)(bb * 203 + 6 + pp)) * 768 + col] = v;
          }
        }
      }
    }
  }
}

// ---------------- round-7 cand body (32x128 tile, dbuf 2-phase) ----------------
DEVINL void cand_body(const u16* __restrict__ hid, const u16* __restrict__ wao,
                      const float* __restrict__ bout, const int* __restrict__ rstar,
                      const float* __restrict__ wstar, float* __restrict__ out,
                      int bx, int g, int bz, char* smem) {
  const int n = g >> 1, r = g & 1;
  const int src_a = (r == 0) ? (n >> 1) : (3 + (n & 1));
  const int dst_a = (r == 1) ? (n >> 1) : (3 + (n & 1));
  const int tn = bx * 128;
  const int b0 = bz * 32;
  const int tid = threadIdx.x, lane = tid & 63, wid = tid >> 6;
  const u16* Bbase = wao + (size_t)dst_a * 768 * 3072;
  const u16* Abase = hid + (size_t)src_a * 3072 + (size_t)n * 15360;

  f32x4 acc[2][2] = {};

  auto stage = [&](int buf, int t) {
    const int k0 = t << 6;
    {
      const int row = tid >> 3;
      const int slA = (tid & 7) ^ (row & 7);
      async_load16(Abase + (size_t)(b0 + row) * 6 * 15360 + k0 + slA * 8,
                   smem + buf * 4096 + row * 128 + (tid & 7) * 16);
    }
#pragma unroll
    for (int j = 0; j < 4; ++j) {
      const int row = j * 32 + (tid >> 3);
      const int slB = (tid & 7) ^ (row & 7);
      async_load16(Bbase + (size_t)(tn + row) * 3072 + k0 + slB * 8,
                   smem + 8192 + buf * 16384 + row * 128 + (tid & 7) * 16);
    }
  };
  auto compute = [&](int buf) {
    const u16* as = (const u16*)(smem + buf * 4096);
    const u16* bs = (const u16*)(smem + 8192 + buf * 16384);
#pragma unroll
    for (int kk = 0; kk < 2; ++kk) {
      bf16x8 af[2], bfv[2];
#pragma unroll
      for (int im = 0; im < 2; ++im) {
        const int R = im * 16 + (lane & 15);
        const int s = (kk * 4 + (lane >> 4)) ^ (R & 7);
        af[im] = *(const bf16x8*)(as + R * 64 + s * 8);
      }
#pragma unroll
      for (int q = 0; q < 2; ++q) {
        const int R = wid * 32 + q * 16 + (lane & 15);
        const int s = (kk * 4 + (lane >> 4)) ^ (R & 7);
        bfv[q] = *(const bf16x8*)(bs + R * 64 + s * 8);
      }
#pragma unroll
      for (int im = 0; im < 2; ++im)
#pragma unroll
        for (int q = 0; q < 2; ++q)
          acc[im][q] = MFMA16(af[im], bfv[q], acc[im][q], 0, 0, 0);
    }
  };

  stage(0, 0);
  __syncthreads();
  for (int t = 0; t < 48; ++t) {
    if (t + 1 < 48) stage((t + 1) & 1, t + 1);
    compute(t & 1);
    __syncthreads();
  }

  const int cn = lane & 15, cr4 = (lane >> 4) * 4;
#pragma unroll
  for (int im = 0; im < 2; ++im)
#pragma unroll
    for (int q = 0; q < 2; ++q) {
      const int col = tn + wid * 32 + q * 16 + cn;
      const float bv = bout[dst_a * 768 + col];
#pragma unroll
      for (int j = 0; j < 4; ++j) {
        const int b = b0 + im * 16 + cr4 + j;
        const int idx = b * 6 + n;
        if (rstar[idx] == r)
          out[((size_t)(b * 203 + n)) * 768 + col] = (acc[im][q][j] + bv) * wstar[idx];
      }
    }
}

// ---------------- dispatch 2: fc1 (2376) + hid (360) + w2/wao cvt backfill (13824) ----------------
__global__ __launch_bounds__(256, 2) void gemm_f1(
    const u16* __restrict__ xp, const u16* __restrict__ w1, const float* __restrict__ fc1b,
    u16* __restrict__ hb,
    const u16* __restrict__ xc, const u16* __restrict__ wai, const float* __restrict__ aib,
    u16* __restrict__ hidb,
    const float* __restrict__ fc2w, u16* __restrict__ w2,
    const float* __restrict__ aow, u16* __restrict__ wao) {
  __shared__ u16 As[128 * 64];
  __shared__ u16 Bs[128 * 64];
  int id = blockIdx.x;
  if (id < 2376) {
    gemm_body<0>(xp, w1, fc1b, hb, 12608, 768, 3072, id % 24, id / 24, As, Bs);
  } else if (id < 2736) {
    id -= 2376;
    gemm_body<0>(xc, wai, aib, hidb, 384, 768, 15360, id % 120, id / 120, As, Bs);
  } else {
    // w2 (2304) + wao (11520) conversions: consumed only by gemm_f2; backfill final round.
    id -= 2736;
    const float* s; u16* d;
    if (id < 2304) { s = fc2w; d = w2; }
    else { s = aow; d = wao; id -= 2304; }
    const int i = (id * 256 + threadIdx.x) * 4;
    const float4 v = *(const float4*)(s + i);
    ushort4 u;
    u.x = f2bf(v.x); u.y = f2bf(v.y); u.z = f2bf(v.z); u.w = f2bf(v.w);
    *(ushort4*)(d + i) = u;
  }
}

// ---------------- dispatch 3: fc2 (594, XCD-swizzled) + cand (144) ----------------
__global__ __launch_bounds__(256, 2) void gemm_f2(
    const u16* __restrict__ hb, const u16* __restrict__ w2, const float* __restrict__ fc2b,
    float* __restrict__ out,
    const u16* __restrict__ hidb, const u16* __restrict__ wao, const float* __restrict__ aob,
    const int* __restrict__ rstar, const float* __restrict__ wstar) {
  __shared__ char smem[40960];
  int id = blockIdx.x;
  if (id < 594) {
    // m204 bijective chunking for nwg=594: q=74, r=2
    const int xcd = id & 7, k = id >> 3;
    id = (xcd < 2 ? xcd * 75 : 150 + (xcd - 2) * 74) + k;
    gemm_body<1>(hb, w2, fc2b, out, 12608, 3072, 768, id % 6, id / 6,
                 (u16*)smem, (u16*)(smem + 16384));
  } else {
    id -= 594;
    cand_body(hidb, wao, aob, rstar, wstar, out, id % 6, (id / 6) % 12, id / 72, smem);
  }
}

// ---------------- launch ----------------
extern "C" void kernel_launch(void* const* d_in, const int* in_sizes, int n_in,
                              void* d_out, int out_size, void* d_ws, size_t ws_size,
                              hipStream_t stream) {
  const float* x     = (const float*)d_in[0];
  const float* fc1w  = (const float*)d_in[1];
  const float* fc1b  = (const float*)d_in[2];
  const float* fc2w  = (const float*)d_in[3];
  const float* fc2b  = (const float*)d_in[4];
  const float* gpair = (const float*)d_in[5];
  const float* aiw   = (const float*)d_in[6];
  const float* aib   = (const float*)d_in[7];
  const float* aow   = (const float*)d_in[8];
  const float* aob   = (const float*)d_in[9];
  const float* bbias = (const float*)d_in[10];
  float* out = (float*)d_out;

  char* ws = (char*)d_ws;
  u16* xp   = (u16*)(ws + 0);          // 12608x768 bf16
  u16* xc   = (u16*)(ws + 19365888);   // 384x768
  u16* w1   = (u16*)(ws + 19955712);   // 3072x768
  u16* w2   = (u16*)(ws + 24674304);   // 768x3072
  u16* wai  = (u16*)(ws + 29392896);   // 5x3072x768
  u16* wao  = (u16*)(ws + 52985856);   // 5x768x3072
  u16* hb   = (u16*)(ws + 76578816);   // 12608x3072
  u16* hid  = (u16*)(ws + 154042368);  // 384x15360
  int*   rstar = (int*)(ws + 165838848);
  float* wstar = (float*)(ws + 165840384);
  if (ws_size < 165841920) return;

  // dispatch 1: x split + w1/wai cvt + gate (23664 blocks)
  cvt_gate<<<23664, 256, 0, stream>>>(x, xc, xp, fc1w, w1, aiw, wai,
                                      gpair, bbias, rstar, wstar);
  // dispatch 2: fc1 + hid_all + w2/wao cvt backfill (16560 blocks)
  gemm_f1<<<16560, 256, 0, stream>>>(xp, w1, fc1b, hb, xc, wai, aib, hid,
                                     fc2w, w2, aow, wao);
  // dispatch 3: fc2 + route candidates (738 blocks)
  gemm_f2<<<738, 256, 0, stream>>>(hb, w2, fc2b, out, hid, wao, aob, rstar, wstar);
}